// Round 4
// baseline (44.021 us; speedup 1.0000x reference)
//
#include <hip/hip_runtime.h>
#include <math.h>

#define Bdim 64
#define Tdim 512
#define Sdim 400
#define Hdim 768
#define Ldim 9

#define PROJ_BLOCKS 768
#define PROJ_WAVES (PROJ_BLOCKS * 4)

// ---------------------------------------------------------------------------
// Kernel 1: per batch row b (512 threads, shfl-based scans, 5 barriers total):
//   pos2tok[b,p] = token index of p-th valid token (p < nvalid), else -1
//   wstart[b,s]  = exclusive prefix of ids_lens
//   nvalid[b]    = total valid tokens
// Also zeroes the loss accumulators (d_ws is NOT re-poisoned between replays).
// ---------------------------------------------------------------------------
__global__ __launch_bounds__(Tdim) void setup_kernel(
    const int* __restrict__ attn, const int* __restrict__ ids_lens,
    int* __restrict__ pos2tok, int* __restrict__ wstart,
    int* __restrict__ nvalid, float* __restrict__ accum,
    unsigned* __restrict__ counter) {
  int b = blockIdx.x;
  int tid = threadIdx.x;
  int lane = tid & 63, wid = tid >> 6;
  __shared__ int wsum[8];
  __shared__ int totsm;

  if (b == 0 && tid < 2) accum[tid] = 0.0f;
  if (b == 0 && tid == 2) *counter = 0u;

  // ---- scan 1: attention mask (inclusive over 512) ----
  int m = attn[b * Tdim + tid];
  int x = m;
#pragma unroll
  for (int off = 1; off < 64; off <<= 1) {
    int v = __shfl_up(x, off, 64);
    if (lane >= off) x += v;
  }
  if (lane == 63) wsum[wid] = x;
  __syncthreads();
  if (tid < 8) {  // exclusive scan of the 8 wave sums (lanes 0..7 of wave 0)
    int s = wsum[tid];
    int y = s;
#pragma unroll
    for (int off = 1; off < 8; off <<= 1) {
      int v = __shfl_up(y, off, 64);
      if (tid >= off) y += v;
    }
    wsum[tid] = y - s;
    if (tid == 7) totsm = y;
  }
  __syncthreads();
  int total = totsm;
  x += wsum[wid];  // block-wide inclusive count of valid in [0..tid]
  if (m) {
    pos2tok[b * Tdim + x - 1] = tid;                       // q-th valid -> t
  } else {
    pos2tok[b * Tdim + total + (tid - x)] = -1;            // bijective fill
  }
  if (tid == 0) nvalid[b] = total;
  __syncthreads();  // protect wsum reuse

  // ---- scan 2: ids_lens (S=400, pad with 0) ----
  int len = (tid < Sdim) ? ids_lens[b * Sdim + tid] : 0;
  int x2 = len;
#pragma unroll
  for (int off = 1; off < 64; off <<= 1) {
    int v = __shfl_up(x2, off, 64);
    if (lane >= off) x2 += v;
  }
  if (lane == 63) wsum[wid] = x2;
  __syncthreads();
  if (tid < 8) {
    int s = wsum[tid];
    int y = s;
#pragma unroll
    for (int off = 1; off < 8; off <<= 1) {
      int v = __shfl_up(y, off, 64);
      if (tid >= off) y += v;
    }
    wsum[tid] = y - s;
  }
  __syncthreads();
  x2 += wsum[wid];
  if (tid < Sdim) wstart[b * Sdim + tid] = x2 - len;  // exclusive prefix
}

// ---------------------------------------------------------------------------
// Kernel 2: wave-per-valid-token projection. proj[b,q,:] = enc[b,pos2tok[b,q],:] @ W
// W fragment (108 floats) register-resident per lane; rows read as float4.
// Single gate load (pos2tok<0) — no dependent nvalid lookup.
// ---------------------------------------------------------------------------
__global__ __launch_bounds__(256, 3) void proj_kernel(
    const float* __restrict__ enc, const float* __restrict__ W,
    const int* __restrict__ pos2tok, float* __restrict__ proj) {
  int tid = threadIdx.x;
  int lane = tid & 63;
  int wid = blockIdx.x * 4 + (tid >> 6);

  // per-lane W fragment: h = 4*lane + 256*k + j, k<3, j<4
  float wf[3][4][Ldim];
#pragma unroll
  for (int k = 0; k < 3; ++k)
#pragma unroll
    for (int j = 0; j < 4; ++j) {
      int h = 4 * lane + 256 * k + j;
#pragma unroll
      for (int l = 0; l < Ldim; ++l) wf[k][j][l] = W[(size_t)h * Ldim + l];
    }

  const float4* encf4 = (const float4*)enc;
  for (int p = wid; p < Bdim * Tdim; p += PROJ_WAVES) {
    int t = pos2tok[p];
    if (t < 0) continue;  // wave-uniform skip (pad slot)
    int b = p >> 9;       // Tdim == 512
    const float4* row = encf4 + ((size_t)(b << 9) + t) * (Hdim / 4);
    float4 x0 = row[lane];
    float4 x1 = row[lane + 64];
    float4 x2 = row[lane + 128];

    float d[Ldim];
#pragma unroll
    for (int l = 0; l < Ldim; ++l) {
      d[l] = x0.x * wf[0][0][l] + x0.y * wf[0][1][l] +
             x0.z * wf[0][2][l] + x0.w * wf[0][3][l] +
             x1.x * wf[1][0][l] + x1.y * wf[1][1][l] +
             x1.z * wf[1][2][l] + x1.w * wf[1][3][l] +
             x2.x * wf[2][0][l] + x2.y * wf[2][1][l] +
             x2.z * wf[2][2][l] + x2.w * wf[2][3][l];
    }
#pragma unroll
    for (int l = 0; l < Ldim; ++l) {
#pragma unroll
      for (int mm = 32; mm > 0; mm >>= 1) d[l] += __shfl_xor(d[l], mm, 64);
    }
    // extract d[lane] without runtime register indexing (avoid scratch)
    float v = d[0];
#pragma unroll
    for (int l = 1; l < Ldim; ++l) v = (lane == l) ? d[l] : v;
    if (lane < Ldim) proj[(size_t)p * Ldim + lane] = v;
  }
}

// ---------------------------------------------------------------------------
// Kernel 3: thread-per-word. Sum 1..len proj rows (L2-resident), mean, +bias,
// argmax -> out; NLL block-reduced, then last-block finalize (100 block-level
// atomics only; the 51200 same-line atomics of R1 were the 300us killer).
// ---------------------------------------------------------------------------
__global__ __launch_bounds__(256) void word_kernel(
    const float* __restrict__ proj, const float* __restrict__ bias,
    const int* __restrict__ ids_lens, const int* __restrict__ label_ids,
    const int* __restrict__ wstart, const int* __restrict__ nvalid,
    float* __restrict__ out, float* __restrict__ accum,
    unsigned* __restrict__ counter) {
  int bs = blockIdx.x * 256 + threadIdx.x;  // grid covers exactly B*S
  int b = bs / Sdim;
  int len = ids_lens[bs];

  float s[Ldim];
#pragma unroll
  for (int l = 0; l < Ldim; ++l) s[l] = 0.0f;

  if (len > 0) {
    int start = wstart[bs];
    int nv = nvalid[b];
    for (int j = 0; j < len; ++j) {
      int q = start + j;
      if (q >= nv) break;
      const float* pr = proj + ((size_t)(b << 9) + q) * Ldim;
#pragma unroll
      for (int l = 0; l < Ldim; ++l) s[l] += pr[l];
    }
  }
  float inv = (len > 0) ? 1.0f / (float)len : 0.0f;
  float lg[Ldim];
#pragma unroll
  for (int l = 0; l < Ldim; ++l) lg[l] = s[l] * inv + bias[l];

  // argmax, first occurrence (matches jnp.argmax)
  int amax = 0;
  float mx = lg[0];
#pragma unroll
  for (int l = 1; l < Ldim; ++l)
    if (lg[l] > mx) { mx = lg[l]; amax = l; }
  out[1 + bs] = (float)amax;

  float nll = 0.0f, cnt = 0.0f;
  if (len > 0) {
    float se = 0.0f;
#pragma unroll
    for (int l = 0; l < Ldim; ++l) se += expf(lg[l] - mx);
    float lse = mx + logf(se);
    int lab = label_ids[bs];
    float ll = lg[0];
#pragma unroll
    for (int l = 1; l < Ldim; ++l) ll = (lab == l) ? lg[l] : ll;
    nll = lse - ll;
    cnt = 1.0f;
  }

#pragma unroll
  for (int off = 32; off > 0; off >>= 1) {
    nll += __shfl_down(nll, off, 64);
    cnt += __shfl_down(cnt, off, 64);
  }
  __shared__ float ss[4], cc[4];
  int wid = threadIdx.x >> 6, lane = threadIdx.x & 63;
  if (lane == 0) { ss[wid] = nll; cc[wid] = cnt; }
  __syncthreads();
  if (threadIdx.x == 0) {
    atomicAdd(&accum[0], ss[0] + ss[1] + ss[2] + ss[3]);
    atomicAdd(&accum[1], cc[0] + cc[1] + cc[2] + cc[3]);
    __threadfence();
    unsigned prev = atomicAdd(counter, 1u);
    if (prev == gridDim.x - 1) {  // last block: all adds visible
      __threadfence();
      float S = atomicAdd(&accum[0], 0.0f);  // atomic read (coherent point)
      float C = atomicAdd(&accum[1], 0.0f);
      out[0] = S / C;
    }
  }
}

extern "C" void kernel_launch(void* const* d_in, const int* in_sizes, int n_in,
                              void* d_out, int out_size, void* d_ws, size_t ws_size,
                              hipStream_t stream) {
  const float* enc      = (const float*)d_in[0];  // [B,T,H] f32
  const float* W        = (const float*)d_in[1];  // [H,L]   f32
  const float* bias     = (const float*)d_in[2];  // [L]     f32
  const int* attn       = (const int*)d_in[3];    // [B,T]   i32
  const int* ids_lens   = (const int*)d_in[4];    // [B,S]   i32
  const int* label_ids  = (const int*)d_in[5];    // [B,S]   i32
  // d_in[6] label_mask is recomputed from ids_lens>0

  float* out = (float*)d_out;  // [1 + B*S]: loss, then argmax as float

  char* ws = (char*)d_ws;
  size_t off0 = 0;
  int* pos2tok     = (int*)(ws + off0);      off0 += (size_t)Bdim * Tdim * sizeof(int);
  int* wstart      = (int*)(ws + off0);      off0 += (size_t)Bdim * Sdim * sizeof(int);
  int* nvalid      = (int*)(ws + off0);      off0 += 256;
  float* accum     = (float*)(ws + off0);    off0 += 128;
  unsigned* counter = (unsigned*)(ws + off0); off0 += 128;
  float* proj      = (float*)(ws + off0);    off0 += (size_t)Bdim * Tdim * Ldim * sizeof(float);

  int word_blocks = (Bdim * Sdim) / 256;  // 100, exact

  setup_kernel<<<Bdim, Tdim, 0, stream>>>(attn, ids_lens, pos2tok, wstart,
                                          nvalid, accum, counter);
  proj_kernel<<<PROJ_BLOCKS, 256, 0, stream>>>(enc, W, pos2tok, proj);
  word_kernel<<<word_blocks, 256, 0, stream>>>(proj, bias, ids_lens, label_ids,
                                               wstart, nvalid, out, accum, counter);
}

// Round 5
// 40.770 us; speedup vs baseline: 1.0797x; 1.0797x over previous
//
#include <hip/hip_runtime.h>
#include <math.h>

#define Bdim 64
#define Tdim 512
#define Sdim 400
#define Hdim 768
#define Ldim 9
#define PSTRIDE 12  // padded proj row stride (16B-aligned stores)

#define PROJ_BLOCKS 1024  // 4096 waves x 8 tokens = 32768 slots exactly

// ---------------------------------------------------------------------------
// DPP 64-lane sum: row_shr 1/2/4/8 then row_bcast 15/31. old=0 => lanes with
// no valid source add 0. Full sum lands in lane 63. Pure VALU (no DS pipe).
// ---------------------------------------------------------------------------
template <int CTRL>
__device__ __forceinline__ float dpp_add(float x) {
  int y = __builtin_amdgcn_update_dpp(0, __float_as_int(x), CTRL, 0xF, 0xF, false);
  return x + __int_as_float(y);
}
__device__ __forceinline__ float wave_sum63(float x) {
  x = dpp_add<0x111>(x);  // row_shr:1
  x = dpp_add<0x112>(x);  // row_shr:2
  x = dpp_add<0x114>(x);  // row_shr:4
  x = dpp_add<0x118>(x);  // row_shr:8
  x = dpp_add<0x142>(x);  // row_bcast:15
  x = dpp_add<0x143>(x);  // row_bcast:31
  return x;               // lane 63 = sum of all 64 lanes
}

// ---------------------------------------------------------------------------
// Kernel 1: per batch row b (512 threads, shfl scans):
//   pos2tok[b,p] = token index of p-th valid token (p < nvalid), else -1
//   wstart[b,s]  = exclusive prefix of ids_lens
//   nvalid[b]    = total valid tokens
// Zeroes loss accumulators (d_ws is NOT re-poisoned between replays).
// ---------------------------------------------------------------------------
__global__ __launch_bounds__(Tdim) void setup_kernel(
    const int* __restrict__ attn, const int* __restrict__ ids_lens,
    int* __restrict__ pos2tok, int* __restrict__ wstart,
    int* __restrict__ nvalid, float* __restrict__ accum,
    unsigned* __restrict__ counter) {
  int b = blockIdx.x;
  int tid = threadIdx.x;
  int lane = tid & 63, wid = tid >> 6;
  __shared__ int wsum[8];
  __shared__ int totsm;

  if (b == 0 && tid < 2) accum[tid] = 0.0f;
  if (b == 0 && tid == 2) *counter = 0u;

  // ---- scan 1: attention mask (inclusive over 512) ----
  int m = attn[b * Tdim + tid];
  int x = m;
#pragma unroll
  for (int off = 1; off < 64; off <<= 1) {
    int v = __shfl_up(x, off, 64);
    if (lane >= off) x += v;
  }
  if (lane == 63) wsum[wid] = x;
  __syncthreads();
  if (tid < 8) {
    int s = wsum[tid];
    int y = s;
#pragma unroll
    for (int off = 1; off < 8; off <<= 1) {
      int v = __shfl_up(y, off, 64);
      if (tid >= off) y += v;
    }
    wsum[tid] = y - s;
    if (tid == 7) totsm = y;
  }
  __syncthreads();
  int total = totsm;
  x += wsum[wid];
  if (m) {
    pos2tok[b * Tdim + x - 1] = tid;             // q-th valid -> t
  } else {
    pos2tok[b * Tdim + total + (tid - x)] = -1;  // bijective pad fill
  }
  if (tid == 0) nvalid[b] = total;
  __syncthreads();

  // ---- scan 2: ids_lens (S=400, pad with 0) ----
  int len = (tid < Sdim) ? ids_lens[b * Sdim + tid] : 0;
  int x2 = len;
#pragma unroll
  for (int off = 1; off < 64; off <<= 1) {
    int v = __shfl_up(x2, off, 64);
    if (lane >= off) x2 += v;
  }
  if (lane == 63) wsum[wid] = x2;
  __syncthreads();
  if (tid < 8) {
    int s = wsum[tid];
    int y = s;
#pragma unroll
    for (int off = 1; off < 8; off <<= 1) {
      int v = __shfl_up(y, off, 64);
      if (tid >= off) y += v;
    }
    wsum[tid] = y - s;
  }
  __syncthreads();
  x2 += wsum[wid];
  if (tid < Sdim) wstart[b * Sdim + tid] = x2 - len;
}

// ---------------------------------------------------------------------------
// Kernel 2: wave-per-token projection, 8 tokens/wave fixed, gates prefetched.
// proj[b,q,:] = enc[b,pos2tok[b,q],:] @ W. W fragment (108 f) in registers;
// rows read as 3x float4/lane; DPP reduce (no DS ops); lane 63 stores 12-
// float padded row (2x float4 + 1).
// ---------------------------------------------------------------------------
__global__ __launch_bounds__(256, 3) void proj_kernel(
    const float* __restrict__ enc, const float* __restrict__ W,
    const int* __restrict__ pos2tok, float* __restrict__ proj) {
  int tid = threadIdx.x;
  int lane = tid & 63;
  int wv = blockIdx.x * 4 + (tid >> 6);
  int base = wv * 8;

  // per-lane W fragment: h = 4*lane + 256*k + j, k<3, j<4
  float wf[3][4][Ldim];
#pragma unroll
  for (int k = 0; k < 3; ++k)
#pragma unroll
    for (int j = 0; j < 4; ++j) {
      int h = 4 * lane + 256 * k + j;
#pragma unroll
      for (int l = 0; l < Ldim; ++l) wf[k][j][l] = W[(size_t)h * Ldim + l];
    }

  // prefetch the 8 gates (wave-uniform addresses)
  int4 g0 = *(const int4*)(pos2tok + base);
  int4 g1 = *(const int4*)(pos2tok + base + 4);

  const float4* encf4 = (const float4*)enc;

  auto step = [&](int t, int p) {
    if (t < 0) return;  // pad slot (wave-uniform skip)
    int b = p >> 9;     // Tdim == 512
    const float4* row = encf4 + ((size_t)(b << 9) + t) * (Hdim / 4);
    float4 x0 = row[lane];
    float4 x1 = row[lane + 64];
    float4 x2 = row[lane + 128];

    float d[Ldim];
#pragma unroll
    for (int l = 0; l < Ldim; ++l) {
      d[l] = x0.x * wf[0][0][l] + x0.y * wf[0][1][l] +
             x0.z * wf[0][2][l] + x0.w * wf[0][3][l] +
             x1.x * wf[1][0][l] + x1.y * wf[1][1][l] +
             x1.z * wf[1][2][l] + x1.w * wf[1][3][l] +
             x2.x * wf[2][0][l] + x2.y * wf[2][1][l] +
             x2.z * wf[2][2][l] + x2.w * wf[2][3][l];
    }
#pragma unroll
    for (int l = 0; l < Ldim; ++l) d[l] = wave_sum63(d[l]);

    if (lane == 63) {
      float4 o0 = make_float4(d[0], d[1], d[2], d[3]);
      float4 o1 = make_float4(d[4], d[5], d[6], d[7]);
      float* dst = proj + (size_t)p * PSTRIDE;
      *(float4*)(dst) = o0;
      *(float4*)(dst + 4) = o1;
      dst[8] = d[8];
    }
  };

  step(g0.x, base + 0);
  step(g0.y, base + 1);
  step(g0.z, base + 2);
  step(g0.w, base + 3);
  step(g1.x, base + 4);
  step(g1.y, base + 5);
  step(g1.z, base + 6);
  step(g1.w, base + 7);
}

// ---------------------------------------------------------------------------
// Kernel 3: thread-per-word. Sum 1..len proj rows (L2-resident), mean, +bias,
// argmax -> out; NLL block-reduced; last block finalizes loss.
// ---------------------------------------------------------------------------
__global__ __launch_bounds__(256) void word_kernel(
    const float* __restrict__ proj, const float* __restrict__ bias,
    const int* __restrict__ ids_lens, const int* __restrict__ label_ids,
    const int* __restrict__ wstart, const int* __restrict__ nvalid,
    float* __restrict__ out, float* __restrict__ accum,
    unsigned* __restrict__ counter) {
  int bs = blockIdx.x * 256 + threadIdx.x;  // grid covers exactly B*S
  int b = bs / Sdim;
  int len = ids_lens[bs];

  float s[Ldim];
#pragma unroll
  for (int l = 0; l < Ldim; ++l) s[l] = 0.0f;

  if (len > 0) {
    int start = wstart[bs];
    int nv = nvalid[b];
    for (int j = 0; j < len; ++j) {
      int q = start + j;
      if (q >= nv) break;
      const float* pr = proj + ((size_t)(b << 9) + q) * PSTRIDE;
#pragma unroll
      for (int l = 0; l < Ldim; ++l) s[l] += pr[l];
    }
  }
  float inv = (len > 0) ? 1.0f / (float)len : 0.0f;
  float lg[Ldim];
#pragma unroll
  for (int l = 0; l < Ldim; ++l) lg[l] = s[l] * inv + bias[l];

  int amax = 0;
  float mx = lg[0];
#pragma unroll
  for (int l = 1; l < Ldim; ++l)
    if (lg[l] > mx) { mx = lg[l]; amax = l; }
  out[1 + bs] = (float)amax;

  float nll = 0.0f, cnt = 0.0f;
  if (len > 0) {
    float se = 0.0f;
#pragma unroll
    for (int l = 0; l < Ldim; ++l) se += expf(lg[l] - mx);
    float lse = mx + logf(se);
    int lab = label_ids[bs];
    float ll = lg[0];
#pragma unroll
    for (int l = 1; l < Ldim; ++l) ll = (lab == l) ? lg[l] : ll;
    nll = lse - ll;
    cnt = 1.0f;
  }

#pragma unroll
  for (int off = 32; off > 0; off >>= 1) {
    nll += __shfl_down(nll, off, 64);
    cnt += __shfl_down(cnt, off, 64);
  }
  __shared__ float ss[4], cc[4];
  int wid = threadIdx.x >> 6, lane = threadIdx.x & 63;
  if (lane == 0) { ss[wid] = nll; cc[wid] = cnt; }
  __syncthreads();
  if (threadIdx.x == 0) {
    atomicAdd(&accum[0], ss[0] + ss[1] + ss[2] + ss[3]);
    atomicAdd(&accum[1], cc[0] + cc[1] + cc[2] + cc[3]);
    __threadfence();
    unsigned prev = atomicAdd(counter, 1u);
    if (prev == gridDim.x - 1) {
      __threadfence();
      float S = atomicAdd(&accum[0], 0.0f);
      float C = atomicAdd(&accum[1], 0.0f);
      out[0] = S / C;
    }
  }
}

extern "C" void kernel_launch(void* const* d_in, const int* in_sizes, int n_in,
                              void* d_out, int out_size, void* d_ws, size_t ws_size,
                              hipStream_t stream) {
  const float* enc      = (const float*)d_in[0];  // [B,T,H] f32
  const float* W        = (const float*)d_in[1];  // [H,L]   f32
  const float* bias     = (const float*)d_in[2];  // [L]     f32
  const int* attn       = (const int*)d_in[3];    // [B,T]   i32
  const int* ids_lens   = (const int*)d_in[4];    // [B,S]   i32
  const int* label_ids  = (const int*)d_in[5];    // [B,S]   i32
  // d_in[6] label_mask is recomputed from ids_lens>0

  float* out = (float*)d_out;  // [1 + B*S]: loss, then argmax as float

  char* ws = (char*)d_ws;
  size_t off0 = 0;
  int* pos2tok      = (int*)(ws + off0);      off0 += (size_t)Bdim * Tdim * sizeof(int);
  int* wstart       = (int*)(ws + off0);      off0 += (size_t)Bdim * Sdim * sizeof(int);
  int* nvalid       = (int*)(ws + off0);      off0 += 256;
  float* accum      = (float*)(ws + off0);    off0 += 128;
  unsigned* counter = (unsigned*)(ws + off0); off0 += 128;
  float* proj       = (float*)(ws + off0);    off0 += (size_t)Bdim * Tdim * PSTRIDE * sizeof(float);

  int word_blocks = (Bdim * Sdim) / 256;  // 100, exact

  setup_kernel<<<Bdim, Tdim, 0, stream>>>(attn, ids_lens, pos2tok, wstart,
                                          nvalid, accum, counter);
  proj_kernel<<<PROJ_BLOCKS, 256, 0, stream>>>(enc, W, pos2tok, proj);
  word_kernel<<<word_blocks, 256, 0, stream>>>(proj, bias, ids_lens, label_ids,
                                               wstart, nvalid, out, accum, counter);
}

// Round 6
// 39.852 us; speedup vs baseline: 1.1046x; 1.0230x over previous
//
#include <hip/hip_runtime.h>
#include <math.h>

#define Bdim 64
#define Tdim 512
#define Sdim 400
#define Hdim 768
#define Ldim 9
#define PSTRIDE 12  // padded proj row stride (16B-aligned stores)

#define PROJ_BLOCKS 512                 // persistent: 2048 waves
#define NWAVES (PROJ_BLOCKS * 4)        // 2048
#define NPAIR 8                         // 2048 waves * 8 pairs * 2 slots = 32768

// ---------------------------------------------------------------------------
// DPP 64-lane sum: row_shr 1/2/4/8 then row_bcast 15/31. old=0 => lanes with
// no valid source add 0. Full sum lands in lane 63. Pure VALU (no DS pipe).
// ---------------------------------------------------------------------------
template <int CTRL>
__device__ __forceinline__ float dpp_add(float x) {
  int y = __builtin_amdgcn_update_dpp(0, __float_as_int(x), CTRL, 0xF, 0xF, false);
  return x + __int_as_float(y);
}
__device__ __forceinline__ float wave_sum63(float x) {
  x = dpp_add<0x111>(x);  // row_shr:1
  x = dpp_add<0x112>(x);  // row_shr:2
  x = dpp_add<0x114>(x);  // row_shr:4
  x = dpp_add<0x118>(x);  // row_shr:8
  x = dpp_add<0x142>(x);  // row_bcast:15
  x = dpp_add<0x143>(x);  // row_bcast:31
  return x;               // lane 63 = sum of all 64 lanes
}

// ---------------------------------------------------------------------------
// Kernel 1: per batch row b (512 threads, shfl scans):
//   pos2tok[b,p] = token index of p-th valid token (p < nvalid)
//   wstart[b,s]  = exclusive prefix of ids_lens
//   nvalid[b]    = total valid tokens
// Zeroes loss accumulators (d_ws is NOT re-poisoned between replays).
// ---------------------------------------------------------------------------
__global__ __launch_bounds__(Tdim) void setup_kernel(
    const int* __restrict__ attn, const int* __restrict__ ids_lens,
    int* __restrict__ pos2tok, int* __restrict__ wstart,
    int* __restrict__ nvalid, float* __restrict__ accum,
    unsigned* __restrict__ counter) {
  int b = blockIdx.x;
  int tid = threadIdx.x;
  int lane = tid & 63, wid = tid >> 6;
  __shared__ int wsum[8];
  __shared__ int totsm;

  if (b == 0 && tid < 2) accum[tid] = 0.0f;
  if (b == 0 && tid == 2) *counter = 0u;

  // ---- scan 1: attention mask (inclusive over 512) ----
  int m = attn[b * Tdim + tid];
  int x = m;
#pragma unroll
  for (int off = 1; off < 64; off <<= 1) {
    int v = __shfl_up(x, off, 64);
    if (lane >= off) x += v;
  }
  if (lane == 63) wsum[wid] = x;
  __syncthreads();
  if (tid < 8) {
    int s = wsum[tid];
    int y = s;
#pragma unroll
    for (int off = 1; off < 8; off <<= 1) {
      int v = __shfl_up(y, off, 64);
      if (tid >= off) y += v;
    }
    wsum[tid] = y - s;
    if (tid == 7) totsm = y;
  }
  __syncthreads();
  int total = totsm;
  x += wsum[wid];
  if (m) pos2tok[b * Tdim + x - 1] = tid;  // q-th valid -> t
  if (tid == 0) nvalid[b] = total;
  __syncthreads();

  // ---- scan 2: ids_lens (S=400, pad with 0) ----
  int len = (tid < Sdim) ? ids_lens[b * Sdim + tid] : 0;
  int x2 = len;
#pragma unroll
  for (int off = 1; off < 64; off <<= 1) {
    int v = __shfl_up(x2, off, 64);
    if (lane >= off) x2 += v;
  }
  if (lane == 63) wsum[wid] = x2;
  __syncthreads();
  if (tid < 8) {
    int s = wsum[tid];
    int y = s;
#pragma unroll
    for (int off = 1; off < 8; off <<= 1) {
      int v = __shfl_up(y, off, 64);
      if (tid >= off) y += v;
    }
    wsum[tid] = y - s;
  }
  __syncthreads();
  x2 += wsum[wid];
  if (tid < Sdim) wstart[b * Sdim + tid] = x2 - len;
}

// ---------------------------------------------------------------------------
// Kernel 2: persistent wave-per-token projection with software pipeline.
// 2048 waves; W fragment (108 f) loaded ONCE per wave; each wave owns 8
// slot-pairs at stride 2048 (pairs land in different rows -> balanced).
// Ping-pong A/B register sets, LOAD(k+2) issued right after COMP(k) so a
// pair (6 KB) is always in flight per wave. Pad gating is wave-uniform via
// v = nvalid[b]-q0 (pads sit at row tails) -- no per-token gate loads.
// ---------------------------------------------------------------------------
__global__ __launch_bounds__(256) void proj_kernel(
    const float* __restrict__ enc, const float* __restrict__ W,
    const int* __restrict__ pos2tok, const int* __restrict__ nvalid,
    float* __restrict__ proj) {
  int tid = threadIdx.x;
  int lane = tid & 63;
  int wv = blockIdx.x * 4 + (tid >> 6);

  // per-lane W fragment: h = 4*lane + 256*k + j, k<3, j<4
  float wf[3][4][Ldim];
#pragma unroll
  for (int k = 0; k < 3; ++k)
#pragma unroll
    for (int j = 0; j < 4; ++j) {
      int h = 4 * lane + 256 * k + j;
#pragma unroll
      for (int l = 0; l < Ldim; ++l) wf[k][j][l] = W[(size_t)h * Ldim + l];
    }

  const float4* encf4 = (const float4*)enc;

  float4 A00, A01, A02, A10, A11, A12;
  float4 B00, B01, B02, B10, B11, B12;
  int vA = 0, pA = 0, vB = 0, pB = 0;

#define LOADP(S, K)                                                        \
  {                                                                        \
    int p_ = (wv + (K) * NWAVES) * 2;                                      \
    int b_ = p_ >> 9;                                                      \
    int q_ = p_ & 511;                                                     \
    v##S = nvalid[b_] - q_;                                                \
    p##S = p_;                                                             \
    if (v##S >= 1) {                                                       \
      int t_ = pos2tok[p_];                                                \
      const float4* r_ = encf4 + ((size_t)(b_ << 9) + t_) * (Hdim / 4);    \
      S##00 = r_[lane]; S##01 = r_[lane + 64]; S##02 = r_[lane + 128];     \
    }                                                                      \
    if (v##S >= 2) {                                                       \
      int t_ = pos2tok[p_ + 1];                                            \
      const float4* r_ = encf4 + ((size_t)(b_ << 9) + t_) * (Hdim / 4);    \
      S##10 = r_[lane]; S##11 = r_[lane + 64]; S##12 = r_[lane + 128];     \
    }                                                                      \
  }

#define PROJ1(X0, X1, X2, PP)                                              \
  {                                                                        \
    float dd[Ldim];                                                        \
    _Pragma("unroll") for (int l = 0; l < Ldim; ++l) {                     \
      dd[l] = X0.x * wf[0][0][l] + X0.y * wf[0][1][l] +                    \
              X0.z * wf[0][2][l] + X0.w * wf[0][3][l] +                    \
              X1.x * wf[1][0][l] + X1.y * wf[1][1][l] +                    \
              X1.z * wf[1][2][l] + X1.w * wf[1][3][l] +                    \
              X2.x * wf[2][0][l] + X2.y * wf[2][1][l] +                    \
              X2.z * wf[2][2][l] + X2.w * wf[2][3][l];                     \
    }                                                                      \
    _Pragma("unroll") for (int l = 0; l < Ldim; ++l) dd[l] = wave_sum63(dd[l]); \
    if (lane == 63) {                                                      \
      float* dst_ = proj + (size_t)(PP) * PSTRIDE;                         \
      *(float4*)(dst_) = make_float4(dd[0], dd[1], dd[2], dd[3]);          \
      *(float4*)(dst_ + 4) = make_float4(dd[4], dd[5], dd[6], dd[7]);      \
      dst_[8] = dd[8];                                                     \
    }                                                                      \
  }

#define COMPP(S)                                                           \
  {                                                                        \
    if (v##S >= 1) PROJ1(S##00, S##01, S##02, p##S);                       \
    if (v##S >= 2) PROJ1(S##10, S##11, S##12, p##S + 1);                   \
  }

  LOADP(A, 0)
  LOADP(B, 1)
#pragma unroll
  for (int k = 0; k < NPAIR; ++k) {
    if (k & 1) {
      COMPP(B)
      if (k + 2 < NPAIR) LOADP(B, k + 2)
    } else {
      COMPP(A)
      if (k + 2 < NPAIR) LOADP(A, k + 2)
    }
  }
#undef LOADP
#undef PROJ1
#undef COMPP
}

// ---------------------------------------------------------------------------
// Kernel 3: thread-per-word. Sum 1..len proj rows (L2-resident), mean, +bias,
// argmax -> out; NLL block-reduced; last block finalizes loss.
// ---------------------------------------------------------------------------
__global__ __launch_bounds__(256) void word_kernel(
    const float* __restrict__ proj, const float* __restrict__ bias,
    const int* __restrict__ ids_lens, const int* __restrict__ label_ids,
    const int* __restrict__ wstart, const int* __restrict__ nvalid,
    float* __restrict__ out, float* __restrict__ accum,
    unsigned* __restrict__ counter) {
  int bs = blockIdx.x * 256 + threadIdx.x;  // grid covers exactly B*S
  int b = bs / Sdim;
  int len = ids_lens[bs];

  float s[Ldim];
#pragma unroll
  for (int l = 0; l < Ldim; ++l) s[l] = 0.0f;

  if (len > 0) {
    int start = wstart[bs];
    int nv = nvalid[b];
    for (int j = 0; j < len; ++j) {
      int q = start + j;
      if (q >= nv) break;
      const float* pr = proj + ((size_t)(b << 9) + q) * PSTRIDE;
#pragma unroll
      for (int l = 0; l < Ldim; ++l) s[l] += pr[l];
    }
  }
  float inv = (len > 0) ? 1.0f / (float)len : 0.0f;
  float lg[Ldim];
#pragma unroll
  for (int l = 0; l < Ldim; ++l) lg[l] = s[l] * inv + bias[l];

  int amax = 0;
  float mx = lg[0];
#pragma unroll
  for (int l = 1; l < Ldim; ++l)
    if (lg[l] > mx) { mx = lg[l]; amax = l; }
  out[1 + bs] = (float)amax;

  float nll = 0.0f, cnt = 0.0f;
  if (len > 0) {
    float se = 0.0f;
#pragma unroll
    for (int l = 0; l < Ldim; ++l) se += expf(lg[l] - mx);
    float lse = mx + logf(se);
    int lab = label_ids[bs];
    float ll = lg[0];
#pragma unroll
    for (int l = 1; l < Ldim; ++l) ll = (lab == l) ? lg[l] : ll;
    nll = lse - ll;
    cnt = 1.0f;
  }

#pragma unroll
  for (int off = 32; off > 0; off >>= 1) {
    nll += __shfl_down(nll, off, 64);
    cnt += __shfl_down(cnt, off, 64);
  }
  __shared__ float ss[4], cc[4];
  int wid = threadIdx.x >> 6, lane = threadIdx.x & 63;
  if (lane == 0) { ss[wid] = nll; cc[wid] = cnt; }
  __syncthreads();
  if (threadIdx.x == 0) {
    atomicAdd(&accum[0], ss[0] + ss[1] + ss[2] + ss[3]);
    atomicAdd(&accum[1], cc[0] + cc[1] + cc[2] + cc[3]);
    __threadfence();
    unsigned prev = atomicAdd(counter, 1u);
    if (prev == gridDim.x - 1) {
      __threadfence();
      float S = atomicAdd(&accum[0], 0.0f);
      float C = atomicAdd(&accum[1], 0.0f);
      out[0] = S / C;
    }
  }
}

extern "C" void kernel_launch(void* const* d_in, const int* in_sizes, int n_in,
                              void* d_out, int out_size, void* d_ws, size_t ws_size,
                              hipStream_t stream) {
  const float* enc      = (const float*)d_in[0];  // [B,T,H] f32
  const float* W        = (const float*)d_in[1];  // [H,L]   f32
  const float* bias     = (const float*)d_in[2];  // [L]     f32
  const int* attn       = (const int*)d_in[3];    // [B,T]   i32
  const int* ids_lens   = (const int*)d_in[4];    // [B,S]   i32
  const int* label_ids  = (const int*)d_in[5];    // [B,S]   i32
  // d_in[6] label_mask is recomputed from ids_lens>0

  float* out = (float*)d_out;  // [1 + B*S]: loss, then argmax as float

  char* ws = (char*)d_ws;
  size_t off0 = 0;
  int* pos2tok      = (int*)(ws + off0);      off0 += (size_t)Bdim * Tdim * sizeof(int);
  int* wstart       = (int*)(ws + off0);      off0 += (size_t)Bdim * Sdim * sizeof(int);
  int* nvalid       = (int*)(ws + off0);      off0 += 256;
  float* accum      = (float*)(ws + off0);    off0 += 128;
  unsigned* counter = (unsigned*)(ws + off0); off0 += 128;
  float* proj       = (float*)(ws + off0);    off0 += (size_t)Bdim * Tdim * PSTRIDE * sizeof(float);

  int word_blocks = (Bdim * Sdim) / 256;  // 100, exact

  setup_kernel<<<Bdim, Tdim, 0, stream>>>(attn, ids_lens, pos2tok, wstart,
                                          nvalid, accum, counter);
  proj_kernel<<<PROJ_BLOCKS, 256, 0, stream>>>(enc, W, pos2tok, nvalid, proj);
  word_kernel<<<word_blocks, 256, 0, stream>>>(proj, bias, ids_lens, label_ids,
                                               wstart, nvalid, out, accum, counter);
}

// Round 7
// 39.321 us; speedup vs baseline: 1.1195x; 1.0135x over previous
//
#include <hip/hip_runtime.h>
#include <math.h>

#define Bdim 64
#define Tdim 512
#define Sdim 400
#define Hdim 768
#define Ldim 9
#define PSTRIDE 12  // padded proj row stride

#define PROJ_BLOCKS 2048  // 2048 blocks x 16 tokens = 32768 slots
#define TOK_PER_BLK 16

// ---------------------------------------------------------------------------
// DPP 64-lane sum: row_shr 1/2/4/8 then row_bcast 15/31. old=0 => lanes with
// no valid source add 0. Full sum lands in lane 63. Pure VALU (no DS pipe).
// ---------------------------------------------------------------------------
template <int CTRL>
__device__ __forceinline__ float dpp_add(float x) {
  int y = __builtin_amdgcn_update_dpp(0, __float_as_int(x), CTRL, 0xF, 0xF, false);
  return x + __int_as_float(y);
}
__device__ __forceinline__ float wave_sum63(float x) {
  x = dpp_add<0x111>(x);  // row_shr:1
  x = dpp_add<0x112>(x);  // row_shr:2
  x = dpp_add<0x114>(x);  // row_shr:4
  x = dpp_add<0x118>(x);  // row_shr:8
  x = dpp_add<0x142>(x);  // row_bcast:15
  x = dpp_add<0x143>(x);  // row_bcast:31
  return x;               // lane 63 = sum of all 64 lanes
}

// ---------------------------------------------------------------------------
// Kernel 1: per batch row b (512 threads, shfl scans):
//   pos2tok[b,p] = token index of p-th valid token (p < nvalid)
//   wstart[b,s]  = exclusive prefix of ids_lens
//   nvalid[b]    = total valid tokens
// Zeroes loss accumulators (d_ws is NOT re-poisoned between replays).
// ---------------------------------------------------------------------------
__global__ __launch_bounds__(Tdim) void setup_kernel(
    const int* __restrict__ attn, const int* __restrict__ ids_lens,
    int* __restrict__ pos2tok, int* __restrict__ wstart,
    int* __restrict__ nvalid, float* __restrict__ accum,
    unsigned* __restrict__ counter) {
  int b = blockIdx.x;
  int tid = threadIdx.x;
  int lane = tid & 63, wid = tid >> 6;
  __shared__ int wsum[8];
  __shared__ int totsm;

  if (b == 0 && tid < 2) accum[tid] = 0.0f;
  if (b == 0 && tid == 2) *counter = 0u;

  // ---- scan 1: attention mask (inclusive over 512) ----
  int m = attn[b * Tdim + tid];
  int x = m;
#pragma unroll
  for (int off = 1; off < 64; off <<= 1) {
    int v = __shfl_up(x, off, 64);
    if (lane >= off) x += v;
  }
  if (lane == 63) wsum[wid] = x;
  __syncthreads();
  if (tid < 8) {
    int s = wsum[tid];
    int y = s;
#pragma unroll
    for (int off = 1; off < 8; off <<= 1) {
      int v = __shfl_up(y, off, 64);
      if (tid >= off) y += v;
    }
    wsum[tid] = y - s;
    if (tid == 7) totsm = y;
  }
  __syncthreads();
  int total = totsm;
  x += wsum[wid];
  if (m) pos2tok[b * Tdim + x - 1] = tid;  // q-th valid -> t
  if (tid == 0) nvalid[b] = total;
  __syncthreads();

  // ---- scan 2: ids_lens (S=400, pad with 0) ----
  int len = (tid < Sdim) ? ids_lens[b * Sdim + tid] : 0;
  int x2 = len;
#pragma unroll
  for (int off = 1; off < 64; off <<= 1) {
    int v = __shfl_up(x2, off, 64);
    if (lane >= off) x2 += v;
  }
  if (lane == 63) wsum[wid] = x2;
  __syncthreads();
  if (tid < 8) {
    int s = wsum[tid];
    int y = s;
#pragma unroll
    for (int off = 1; off < 8; off <<= 1) {
      int v = __shfl_up(y, off, 64);
      if (tid >= off) y += v;
    }
    wsum[tid] = y - s;
  }
  __syncthreads();
  x2 += wsum[wid];
  if (tid < Sdim) wstart[b * Sdim + tid] = x2 - len;
}

// ---------------------------------------------------------------------------
// Kernel 2: projection, L-split across 3 waves.
// Block = 192 threads = 3 waves; all waves read the SAME 16 token rows
// (redundant issue, cache-dedup'd bytes); wave w computes logits 3w..3w+2.
// W fragment is only 36 floats/lane -> stays register-resident (R5's VGPR=80
// proved the 108-float fragment was silently rematerialized per token).
// Unconditional coalesced float4 row loads (pads clamp to row 0), value-
// select after load; depth-2 buffer pipeline with compile-time indexing.
// ---------------------------------------------------------------------------
__global__ __launch_bounds__(192, 4) void proj_kernel(
    const float* __restrict__ enc, const float* __restrict__ W,
    const int* __restrict__ pos2tok, const int* __restrict__ nvalid,
    float* __restrict__ proj) {
  int tid = threadIdx.x;
  int lane = tid & 63;
  int w = tid >> 6;      // 0..2
  int l0 = w * 3;        // logits slice {l0, l0+1, l0+2}
  int base = blockIdx.x * TOK_PER_BLK;   // 16 slots, all within one batch row
  int b = base >> 9;                     // Tdim == 512
  int vc = nvalid[b] - (base & 511);     // valid tokens in this group
  vc = vc < 0 ? 0 : (vc > TOK_PER_BLK ? TOK_PER_BLK : vc);
  if (vc == 0) return;  // block-uniform early out

  // per-lane W fragment: h = 4*lane + 256*k + j (k<3, j<4), cols l0..l0+2
  float wf[3][4][3];
#pragma unroll
  for (int k = 0; k < 3; ++k)
#pragma unroll
    for (int j = 0; j < 4; ++j) {
      int h = 4 * lane + 256 * k + j;
#pragma unroll
      for (int c = 0; c < 3; ++c) wf[k][j][c] = W[(size_t)h * Ldim + l0 + c];
    }

  const float4* encb = (const float4*)enc + (size_t)(b << 9) * (Hdim / 4);

  float4 xr[2][3];
  // prologue: load tokens 0 and 1 (t clamped to 0 for pad slots)
#pragma unroll
  for (int i = 0; i < 2; ++i) {
    int tv = pos2tok[base + i];
    int t = (i < vc) ? tv : 0;
    const float4* r = encb + (size_t)t * (Hdim / 4);
    xr[i][0] = r[lane];
    xr[i][1] = r[lane + 64];
    xr[i][2] = r[lane + 128];
  }

#pragma unroll
  for (int i = 0; i < TOK_PER_BLK; ++i) {
    float4 x0 = xr[i & 1][0], x1 = xr[i & 1][1], x2 = xr[i & 1][2];
    if (i < vc) {
      float dd[3];
#pragma unroll
      for (int c = 0; c < 3; ++c) {
        dd[c] = x0.x * wf[0][0][c] + x0.y * wf[0][1][c] +
                x0.z * wf[0][2][c] + x0.w * wf[0][3][c] +
                x1.x * wf[1][0][c] + x1.y * wf[1][1][c] +
                x1.z * wf[1][2][c] + x1.w * wf[1][3][c] +
                x2.x * wf[2][0][c] + x2.y * wf[2][1][c] +
                x2.z * wf[2][2][c] + x2.w * wf[2][3][c];
      }
#pragma unroll
      for (int c = 0; c < 3; ++c) dd[c] = wave_sum63(dd[c]);
      if (lane == 63) {
        float* dst = proj + (size_t)(base + i) * PSTRIDE + l0;
        dst[0] = dd[0];
        dst[1] = dd[1];
        dst[2] = dd[2];
      }
    }
    if (i + 2 < TOK_PER_BLK) {  // refill the buffer just consumed
      int tv = pos2tok[base + i + 2];
      int t = (i + 2 < vc) ? tv : 0;
      const float4* r = encb + (size_t)t * (Hdim / 4);
      xr[i & 1][0] = r[lane];
      xr[i & 1][1] = r[lane + 64];
      xr[i & 1][2] = r[lane + 128];
    }
  }
}

// ---------------------------------------------------------------------------
// Kernel 3: thread-per-word. Sum 1..len proj rows (L2-resident), mean, +bias,
// argmax -> out; NLL block-reduced; last block finalizes loss.
// ---------------------------------------------------------------------------
__global__ __launch_bounds__(256) void word_kernel(
    const float* __restrict__ proj, const float* __restrict__ bias,
    const int* __restrict__ ids_lens, const int* __restrict__ label_ids,
    const int* __restrict__ wstart, const int* __restrict__ nvalid,
    float* __restrict__ out, float* __restrict__ accum,
    unsigned* __restrict__ counter) {
  int bs = blockIdx.x * 256 + threadIdx.x;  // grid covers exactly B*S
  int b = bs / Sdim;
  int len = ids_lens[bs];

  float s[Ldim];
#pragma unroll
  for (int l = 0; l < Ldim; ++l) s[l] = 0.0f;

  if (len > 0) {
    int start = wstart[bs];
    int nv = nvalid[b];
    for (int j = 0; j < len; ++j) {
      int q = start + j;
      if (q >= nv) break;
      const float* pr = proj + ((size_t)(b << 9) + q) * PSTRIDE;
#pragma unroll
      for (int l = 0; l < Ldim; ++l) s[l] += pr[l];
    }
  }
  float inv = (len > 0) ? 1.0f / (float)len : 0.0f;
  float lg[Ldim];
#pragma unroll
  for (int l = 0; l < Ldim; ++l) lg[l] = s[l] * inv + bias[l];

  int amax = 0;
  float mx = lg[0];
#pragma unroll
  for (int l = 1; l < Ldim; ++l)
    if (lg[l] > mx) { mx = lg[l]; amax = l; }
  out[1 + bs] = (float)amax;

  float nll = 0.0f, cnt = 0.0f;
  if (len > 0) {
    float se = 0.0f;
#pragma unroll
    for (int l = 0; l < Ldim; ++l) se += expf(lg[l] - mx);
    float lse = mx + logf(se);
    int lab = label_ids[bs];
    float ll = lg[0];
#pragma unroll
    for (int l = 1; l < Ldim; ++l) ll = (lab == l) ? lg[l] : ll;
    nll = lse - ll;
    cnt = 1.0f;
  }

#pragma unroll
  for (int off = 32; off > 0; off >>= 1) {
    nll += __shfl_down(nll, off, 64);
    cnt += __shfl_down(cnt, off, 64);
  }
  __shared__ float ss[4], cc[4];
  int wid = threadIdx.x >> 6, lane = threadIdx.x & 63;
  if (lane == 0) { ss[wid] = nll; cc[wid] = cnt; }
  __syncthreads();
  if (threadIdx.x == 0) {
    atomicAdd(&accum[0], ss[0] + ss[1] + ss[2] + ss[3]);
    atomicAdd(&accum[1], cc[0] + cc[1] + cc[2] + cc[3]);
    __threadfence();
    unsigned prev = atomicAdd(counter, 1u);
    if (prev == gridDim.x - 1) {
      __threadfence();
      float S = atomicAdd(&accum[0], 0.0f);
      float C = atomicAdd(&accum[1], 0.0f);
      out[0] = S / C;
    }
  }
}

extern "C" void kernel_launch(void* const* d_in, const int* in_sizes, int n_in,
                              void* d_out, int out_size, void* d_ws, size_t ws_size,
                              hipStream_t stream) {
  const float* enc      = (const float*)d_in[0];  // [B,T,H] f32
  const float* W        = (const float*)d_in[1];  // [H,L]   f32
  const float* bias     = (const float*)d_in[2];  // [L]     f32
  const int* attn       = (const int*)d_in[3];    // [B,T]   i32
  const int* ids_lens   = (const int*)d_in[4];    // [B,S]   i32
  const int* label_ids  = (const int*)d_in[5];    // [B,S]   i32
  // d_in[6] label_mask is recomputed from ids_lens>0

  float* out = (float*)d_out;  // [1 + B*S]: loss, then argmax as float

  char* ws = (char*)d_ws;
  size_t off0 = 0;
  int* pos2tok      = (int*)(ws + off0);      off0 += (size_t)Bdim * Tdim * sizeof(int);
  int* wstart       = (int*)(ws + off0);      off0 += (size_t)Bdim * Sdim * sizeof(int);
  int* nvalid       = (int*)(ws + off0);      off0 += 256;
  float* accum      = (float*)(ws + off0);    off0 += 128;
  unsigned* counter = (unsigned*)(ws + off0); off0 += 128;
  float* proj       = (float*)(ws + off0);    off0 += (size_t)Bdim * Tdim * PSTRIDE * sizeof(float);

  int word_blocks = (Bdim * Sdim) / 256;  // 100, exact

  setup_kernel<<<Bdim, Tdim, 0, stream>>>(attn, ids_lens, pos2tok, wstart,
                                          nvalid, accum, counter);
  proj_kernel<<<PROJ_BLOCKS, 192, 0, stream>>>(enc, W, pos2tok, nvalid, proj);
  word_kernel<<<word_blocks, 256, 0, stream>>>(proj, bias, ids_lens, label_ids,
                                               wstart, nvalid, out, accum, counter);
}